// Round 1
// baseline (312.896 us; speedup 1.0000x reference)
//
#include <hip/hip_runtime.h>

#define WAVE 64
#define CAP 64  // per-node bucket capacity; P(deg>=64 | Poisson(16)) ~ 1e-19

typedef __bf16 v8bf __attribute__((ext_vector_type(8)));
typedef __bf16 v4bf __attribute__((ext_vector_type(4)));
typedef __bf16 v2bf __attribute__((ext_vector_type(2)));
typedef float f32x4 __attribute__((ext_vector_type(4)));

// ---------------- prep: wconv(W1) + wconv(W2) only ----------------
// blocks [0,256): W1 transpose/split; [256,288): W2
__global__ __launch_bounds__(256) void prep_kernel(const float* __restrict__ W1,
                                                   const float* __restrict__ W2,
                                                   __bf16* __restrict__ Wt1hi,
                                                   __bf16* __restrict__ Wt1lo,
                                                   __bf16* __restrict__ Wt2hi,
                                                   __bf16* __restrict__ Wt2lo) {
    int b = blockIdx.x;
    int tid = threadIdx.x;
    if (b < 256) {  // W1: K=512, N=128
        int idx = b * 256 + tid;
        int k = idx >> 7, n = idx & 127;
        float v = W1[idx];
        __bf16 h = (__bf16)v;
        Wt1hi[n * 512 + k] = h;
        Wt1lo[n * 512 + k] = (__bf16)(v - (float)h);
    } else {  // W2: K=128, N=64
        int idx = (b - 256) * 256 + tid;
        int k = idx >> 6, n = idx & 63;
        float v = W2[idx];
        __bf16 h = (__bf16)v;
        Wt2hi[n * 128 + k] = h;
        Wt2lo[n * 128 + k] = (__bf16)(v - (float)h);
    }
}

// ---------------- fused: LDS-staged split-bf16 MFMA GEMM + bucket fill ----------------
// blocks [0,NG): gemm tile; [NG, NG+NF): fill (independent, co-scheduled).
// GEMM: C[r,c] = sum_k A[r,k] B[k,c] (NO dinv scaling — applied in gather).
// Fill: p = atomicAdd(cursor[dst]); srcs[dst*CAP+p] = src. cursor becomes degree.
template <int NC, int KK, bool OBF16, bool FILL>
__global__ __launch_bounds__(256, 3) void gemm_fill_kernel(
    const float* __restrict__ A, const __bf16* __restrict__ Bhi,
    const __bf16* __restrict__ Blo, void* __restrict__ Cout, int M, int NG,
    const int* __restrict__ ei, int E, int* __restrict__ cursor,
    int* __restrict__ srcs) {
    constexpr int BK = 32;
    constexpr int LD = 40;  // bf16 stride 80 B: 16B-aligned
    constexpr int NT = NC / 16;
    constexpr int CPT = (NC * 4) / 256;

    __shared__ __bf16 sAhi[128][LD];
    __shared__ __bf16 sAlo[128][LD];
    __shared__ __bf16 sBhi[NC][LD];
    __shared__ __bf16 sBlo[NC][LD];

    const int tid = threadIdx.x;

    if (FILL && blockIdx.x >= NG) {  // ---- fill path: 2 edges per thread ----
        int bb = (blockIdx.x - NG) * 512;
#pragma unroll
        for (int j = 0; j < 2; ++j) {
            int e = bb + tid + j * 256;
            if (e < E) {
                int dst = ei[E + e];
                int p = atomicAdd(&cursor[dst], 1);
                if (p < CAP) srcs[(size_t)dst * CAP + p] = ei[e];
            }
        }
        return;
    }

    const int lane = tid & 63;
    const int wv = tid >> 6;
    const int ln15 = lane & 15;
    const int quad = lane >> 4;
    const int rowBase = blockIdx.x * 128;

    const int sr = tid >> 1;
    const int kh = (tid & 1) * 16;
    const int gr = rowBase + sr;
    const bool aval = gr < M;
    const float* aBase = A + (size_t)gr * KK + kh;

    int bcol[CPT], bg[CPT];
#pragma unroll
    for (int c = 0; c < CPT; ++c) {
        int chunk = tid * CPT + c;
        bcol[c] = chunk >> 2;
        bg[c] = chunk & 3;
    }

    f32x4 acc[2][NT];
#pragma unroll
    for (int rt = 0; rt < 2; ++rt)
#pragma unroll
        for (int t = 0; t < NT; ++t) acc[rt][t] = (f32x4){0.f, 0.f, 0.f, 0.f};

    float4 aR[4];
    v8bf bhR[CPT], blR[CPT];

    auto loadTiles = [&](int k0) {
        if (aval) {
#pragma unroll
            for (int q = 0; q < 4; ++q) aR[q] = *(const float4*)(aBase + k0 + q * 4);
        } else {
#pragma unroll
            for (int q = 0; q < 4; ++q) aR[q] = make_float4(0.f, 0.f, 0.f, 0.f);
        }
#pragma unroll
        for (int c = 0; c < CPT; ++c) {
            bhR[c] = *(const v8bf*)(Bhi + (size_t)bcol[c] * KK + k0 + bg[c] * 8);
            blR[c] = *(const v8bf*)(Blo + (size_t)bcol[c] * KK + k0 + bg[c] * 8);
        }
    };

    loadTiles(0);

    for (int k0 = 0; k0 < KK; k0 += BK) {
        float fv[16];
#pragma unroll
        for (int q = 0; q < 4; ++q) {
            fv[q * 4 + 0] = aR[q].x; fv[q * 4 + 1] = aR[q].y;
            fv[q * 4 + 2] = aR[q].z; fv[q * 4 + 3] = aR[q].w;
        }
#pragma unroll
        for (int g = 0; g < 2; ++g) {
            v8bf hv, lv;
#pragma unroll
            for (int j = 0; j < 8; ++j) {
                float v = fv[g * 8 + j];
                __bf16 h = (__bf16)v;
                hv[j] = h;
                lv[j] = (__bf16)(v - (float)h);
            }
            *(v8bf*)&sAhi[sr][kh + g * 8] = hv;
            *(v8bf*)&sAlo[sr][kh + g * 8] = lv;
        }
#pragma unroll
        for (int c = 0; c < CPT; ++c) {
            *(v8bf*)&sBhi[bcol[c]][bg[c] * 8] = bhR[c];
            *(v8bf*)&sBlo[bcol[c]][bg[c] * 8] = blR[c];
        }
        __syncthreads();

        if (k0 + BK < KK) loadTiles(k0 + BK);

        v8bf ah[2], al[2];
#pragma unroll
        for (int rt = 0; rt < 2; ++rt) {
            int r = wv * 32 + rt * 16 + ln15;
            ah[rt] = *(const v8bf*)&sAhi[r][quad * 8];
            al[rt] = *(const v8bf*)&sAlo[r][quad * 8];
        }
#pragma unroll
        for (int t = 0; t < NT; ++t) {
            v8bf bh = *(const v8bf*)&sBhi[t * 16 + ln15][quad * 8];
            v8bf bl = *(const v8bf*)&sBlo[t * 16 + ln15][quad * 8];
#pragma unroll
            for (int rt = 0; rt < 2; ++rt) {
                acc[rt][t] = __builtin_amdgcn_mfma_f32_16x16x32_bf16(ah[rt], bh, acc[rt][t], 0, 0, 0);
                acc[rt][t] = __builtin_amdgcn_mfma_f32_16x16x32_bf16(al[rt], bh, acc[rt][t], 0, 0, 0);
                acc[rt][t] = __builtin_amdgcn_mfma_f32_16x16x32_bf16(ah[rt], bl, acc[rt][t], 0, 0, 0);
            }
        }
        __syncthreads();
    }

    // C/D layout: col=ln15, row=quad*4+reg
#pragma unroll
    for (int rt = 0; rt < 2; ++rt) {
#pragma unroll
        for (int r = 0; r < 4; ++r) {
            int grow = rowBase + wv * 32 + rt * 16 + quad * 4 + r;
            if (grow < M) {
#pragma unroll
                for (int t = 0; t < NT; ++t) {
                    float v = acc[rt][t][r];
                    if (OBF16)
                        ((__bf16*)Cout)[(size_t)grow * NC + t * 16 + ln15] = (__bf16)v;
                    else
                        ((float*)Cout)[(size_t)grow * NC + t * 16 + ln15] = v;
                }
            }
        }
    }
}

// ---------------- gather-aggregate, dinv on the fly ----------------
// out[n,j] = [relu]( dn*( sum_e ds_e*hs[src_e,j] + dn*hs[n,j] ) + bias[j] ),
// dn = rsqrt(deg[n]+1), ds = rsqrt(deg[src]+1); deg = counts (= cursor after fill)
template <int F, bool RELU, bool BF16OUT>
__global__ __launch_bounds__(256) void gather_agg_bf16(const __bf16* __restrict__ hs,
                                                       const int* __restrict__ counts,
                                                       const int* __restrict__ srcs,
                                                       const float* __restrict__ bias,
                                                       void* __restrict__ outp, int N) {
    int node = blockIdx.x * 4 + (int)(threadIdx.x >> 6);
    if (node >= N) return;
    int lane = threadIdx.x & 63;
    int cnt = counts[node];
    if (cnt > CAP) cnt = CAP;
    int beg = node * CAP;
    int end = beg + cnt;
    float dn = rsqrtf((float)cnt + 1.0f);

    if constexpr (F == 128) {
        int col = 2 * lane;
        float a0, a1;
        {
            v2bf s = *(const v2bf*)&hs[(size_t)node * F + col];
            a0 = dn * (float)s[0];
            a1 = dn * (float)s[1];
        }
        int e = beg;
        for (; e + 4 <= end; e += 4) {
            int s0 = srcs[e], s1 = srcs[e + 1], s2 = srcs[e + 2], s3 = srcs[e + 3];
            float d0 = rsqrtf((float)counts[s0] + 1.0f);
            float d1 = rsqrtf((float)counts[s1] + 1.0f);
            float d2 = rsqrtf((float)counts[s2] + 1.0f);
            float d3 = rsqrtf((float)counts[s3] + 1.0f);
            v2bf r0 = *(const v2bf*)&hs[(size_t)s0 * F + col];
            v2bf r1 = *(const v2bf*)&hs[(size_t)s1 * F + col];
            v2bf r2 = *(const v2bf*)&hs[(size_t)s2 * F + col];
            v2bf r3 = *(const v2bf*)&hs[(size_t)s3 * F + col];
            a0 += d0 * (float)r0[0] + d1 * (float)r1[0] + d2 * (float)r2[0] + d3 * (float)r3[0];
            a1 += d0 * (float)r0[1] + d1 * (float)r1[1] + d2 * (float)r2[1] + d3 * (float)r3[1];
        }
        for (; e < end; ++e) {
            int s0 = srcs[e];
            float d0 = rsqrtf((float)counts[s0] + 1.0f);
            v2bf r0 = *(const v2bf*)&hs[(size_t)s0 * F + col];
            a0 += d0 * (float)r0[0];
            a1 += d0 * (float)r0[1];
        }
        float2 bv = *(const float2*)&bias[col];
        float v0 = dn * a0 + bv.x;
        float v1 = dn * a1 + bv.y;
        if (RELU) {
            v0 = fmaxf(v0, 0.f);
            v1 = fmaxf(v1, 0.f);
        }
        if (BF16OUT) {
            v2bf o;
            o[0] = (__bf16)v0;
            o[1] = (__bf16)v1;
            *(v2bf*)&((__bf16*)outp)[(size_t)node * F + col] = o;
        } else {
            *(float2*)&((float*)outp)[(size_t)node * F + col] = make_float2(v0, v1);
        }
    } else {
        // F == 64: 4 quarter-waves of 16 lanes; each takes every 4th edge;
        // lane covers 4 cols (v4bf). Combine via shfl_xor(16), shfl_xor(32).
        int q = lane >> 4;
        int sl = lane & 15;
        int col = sl * 4;
        float a0 = 0.f, a1 = 0.f, a2 = 0.f, a3 = 0.f;
        if (q == 0) {
            v4bf s = *(const v4bf*)&hs[(size_t)node * F + col];
            a0 = dn * (float)s[0]; a1 = dn * (float)s[1];
            a2 = dn * (float)s[2]; a3 = dn * (float)s[3];
        }
        int e = beg + q;
        for (; e + 4 < end; e += 8) {
            int s0 = srcs[e], s1 = srcs[e + 4];
            float d0 = rsqrtf((float)counts[s0] + 1.0f);
            float d1 = rsqrtf((float)counts[s1] + 1.0f);
            v4bf r0 = *(const v4bf*)&hs[(size_t)s0 * F + col];
            v4bf r1 = *(const v4bf*)&hs[(size_t)s1 * F + col];
            a0 += d0 * (float)r0[0] + d1 * (float)r1[0];
            a1 += d0 * (float)r0[1] + d1 * (float)r1[1];
            a2 += d0 * (float)r0[2] + d1 * (float)r1[2];
            a3 += d0 * (float)r0[3] + d1 * (float)r1[3];
        }
        if (e < end) {
            int s0 = srcs[e];
            float d0 = rsqrtf((float)counts[s0] + 1.0f);
            v4bf r0 = *(const v4bf*)&hs[(size_t)s0 * F + col];
            a0 += d0 * (float)r0[0]; a1 += d0 * (float)r0[1];
            a2 += d0 * (float)r0[2]; a3 += d0 * (float)r0[3];
        }
        a0 += __shfl_xor(a0, 16); a0 += __shfl_xor(a0, 32);
        a1 += __shfl_xor(a1, 16); a1 += __shfl_xor(a1, 32);
        a2 += __shfl_xor(a2, 16); a2 += __shfl_xor(a2, 32);
        a3 += __shfl_xor(a3, 16); a3 += __shfl_xor(a3, 32);
        if (q == 0) {
            float4 bv = *(const float4*)&bias[col];
            float v0 = dn * a0 + bv.x;
            float v1 = dn * a1 + bv.y;
            float v2 = dn * a2 + bv.z;
            float v3 = dn * a3 + bv.w;
            if (RELU) {
                v0 = fmaxf(v0, 0.f); v1 = fmaxf(v1, 0.f);
                v2 = fmaxf(v2, 0.f); v3 = fmaxf(v3, 0.f);
            }
            if (BF16OUT) {
                v4bf o;
                o[0] = (__bf16)v0; o[1] = (__bf16)v1;
                o[2] = (__bf16)v2; o[3] = (__bf16)v3;
                *(v4bf*)&((__bf16*)outp)[(size_t)node * F + col] = o;
            } else {
                *(float4*)&((float*)outp)[(size_t)node * F + col] =
                    make_float4(v0, v1, v2, v3);
            }
        }
    }
}

// ---------------- decode: 4 lanes/edge, bf16 z rows (128 B) ----------------
__global__ __launch_bounds__(256) void decode_bf16_kernel(const __bf16* __restrict__ z,
                                                          const int* __restrict__ pos,
                                                          const int* __restrict__ neg, int E,
                                                          float* __restrict__ out) {
    int tid = blockIdx.x * blockDim.x + threadIdx.x;
    int g = tid >> 2;
    int l = tid & 3;
    int total = 2 * E;
    if (g >= total) return;
    int src, dst;
    if (g < E) {
        src = pos[g];
        dst = pos[E + g];
    } else {
        int e = g - E;
        src = neg[e];
        dst = neg[E + e];
    }
    const __bf16* zs = z + (size_t)src * 64 + l * 16;
    const __bf16* zd = z + (size_t)dst * 64 + l * 16;
    v8bf a0 = *(const v8bf*)zs;
    v8bf a1 = *(const v8bf*)(zs + 8);
    v8bf b0 = *(const v8bf*)zd;
    v8bf b1 = *(const v8bf*)(zd + 8);
    float p = 0.f;
#pragma unroll
    for (int j = 0; j < 8; ++j) p += (float)a0[j] * (float)b0[j] + (float)a1[j] * (float)b1[j];
    p += __shfl_xor(p, 1);
    p += __shfl_xor(p, 2);
    if (l == 0) out[g] = p;
}

extern "C" void kernel_launch(void* const* d_in, const int* in_sizes, int n_in, void* d_out,
                              int out_size, void* d_ws, size_t ws_size, hipStream_t stream) {
    const float* x = (const float*)d_in[0];
    const int* pos_ei = (const int*)d_in[1];
    const int* neg_ei = (const int*)d_in[2];
    const float* W1 = (const float*)d_in[3];
    const float* b1 = (const float*)d_in[4];
    const float* W2 = (const float*)d_in[5];
    const float* b2 = (const float*)d_in[6];
    float* out = (float*)d_out;

    const int IN = 512, HID = 128, OUT = 64;
    const int N = in_sizes[0] / IN;  // 50000
    const int E = in_sizes[1] / 2;   // 800000

    // workspace layout (4-byte units; all chunks multiples of 16 B)
    size_t nAlign = ((size_t)N + 255) & ~(size_t)255;
    float* p = (float*)d_ws;
    float* h1 = p; p += (size_t)N * HID;                 // fp32 N*128
    __bf16* hs1 = (__bf16*)p; p += (size_t)N * HID / 2;  // bf16 N*128
    __bf16* hs2 = (__bf16*)p; p += (size_t)N * OUT / 2;  // bf16 N*64
    __bf16* zbf = (__bf16*)p; p += (size_t)N * OUT / 2;  // bf16 N*64
    int* cursor = (int*)p; p += nAlign;                  // degree counts after fill
    int* srcs = (int*)p; p += (size_t)N * CAP;           // fixed buckets
    __bf16* Wt1hi = (__bf16*)p; p += (size_t)IN * HID / 2;
    __bf16* Wt1lo = (__bf16*)p; p += (size_t)IN * HID / 2;
    __bf16* Wt2hi = (__bf16*)p; p += (size_t)HID * OUT / 2;
    __bf16* Wt2lo = (__bf16*)p; p += (size_t)HID * OUT / 2;

    const int NG = (N + 127) / 128;   // 391 gemm tiles
    const int NF = (E + 511) / 512;   // 1563 fill blocks (2 edges/thread)

    // ---- prep: W transpose/split (tiny); cursor zero ----
    hipMemsetAsync(cursor, 0, (size_t)N * sizeof(int), stream);
    prep_kernel<<<288, 256, 0, stream>>>(W1, W2, Wt1hi, Wt1lo, Wt2hi, Wt2lo);

    // ---- layer 1 GEMM fused with bucket fill (both independent) ----
    gemm_fill_kernel<128, 512, true, true><<<NG + NF, 256, 0, stream>>>(
        x, Wt1hi, Wt1lo, hs1, N, NG, pos_ei, E, cursor, srcs);
    gather_agg_bf16<128, true, false>
        <<<(N + 3) / 4, 256, 0, stream>>>(hs1, cursor, srcs, b1, h1, N);

    // ---- layer 2 ----
    gemm_fill_kernel<64, 128, true, false><<<NG, 256, 0, stream>>>(
        h1, Wt2hi, Wt2lo, hs2, N, NG, nullptr, 0, nullptr, nullptr);
    gather_agg_bf16<64, false, true>
        <<<(N + 3) / 4, 256, 0, stream>>>(hs2, cursor, srcs, b2, zbf, N);

    // ---- decode ----
    decode_bf16_kernel<<<((size_t)2 * E * 4 + 255) / 256, 256, 0, stream>>>(
        zbf, pos_ei, neg_ei, E, out);
}